// Round 4
// baseline (169.637 us; speedup 1.0000x reference)
//
#include <hip/hip_runtime.h>
#include <math.h>

// PyramidROIAlign: B=2, N=1000, C=256, POOL=7x7
// p3: [2,128,128,256], p4: [2,64,64,256], p5: [2,32,32,256], all fp32 NHWC.
// Output: [2,1000,7,7,256] fp32.
//
// R4 (= R3 + compile fix): latency-bound fix. One wave per (box, pool-row iy),
// lane = 4 channels. Phase 1 issues ALL 28 corner 16B loads into registers
// (112 data VGPRs, ~336 loads in flight/CU at 3 waves/SIMD -> Little's law
// target for 6.3 TB/s). Phase 2 lerps + nontemporal-stores (output is
// streaming; keep L2 for feature-map reuse).
// NOTE: __builtin_nontemporal_store needs a clang native vector type, not
// HIP_vector_type -- use ext_vector_type(4).

#define N_PER_B 1000
#define NBOX    2000   // B*N
#define CCH     256
#define PH      7
#define PW      7
#define WAVES_PER_BLOCK 4
#define TOTAL_WAVES (NBOX * PH)   // 14000

typedef float nfloat4 __attribute__((ext_vector_type(4)));

__global__ __launch_bounds__(256, 3) void pyramid_roi_align_kernel(
    const float* __restrict__ boxes,   // [2000,4] y1,x1,y2,x2
    const float* __restrict__ p3,      // [2,128,128,256]
    const float* __restrict__ p4,      // [2,64,64,256]
    const float* __restrict__ p5,      // [2,32,32,256]
    float* __restrict__ out)           // [2000,49,256]
{
    const int wave = blockIdx.x * WAVES_PER_BLOCK + (threadIdx.x >> 6);
    const int lane = threadIdx.x & 63;
    const int c    = lane * 4;

    const int box = wave / PH;
    const int iy  = wave - box * PH;

    // ---- per-box setup (wave-uniform) ----
    const float y1 = boxes[box * 4 + 0];
    const float x1 = boxes[box * 4 + 1];
    const float y2 = boxes[box * 4 + 2];
    const float x2 = boxes[box * 4 + 3];
    const float h  = y2 - y1;
    const float w  = x2 - x1;

    // roi_level = clip(ceil(5 + log(h*w)/log(2)), 3, 5) -- match ref op order
    const float lvl  = ceilf(5.0f + logf(h * w) / 0.69314718055994530942f);
    const float lvlc = fminf(fmaxf(lvl, 3.0f), 5.0f);
    const int level  = (int)lvlc;

    const float* feat;
    int H;
    if (level <= 3)      { feat = p3; H = 128; }
    else if (level == 4) { feat = p4; H = 64;  }
    else                 { feat = p5; H = 32;  }
    const int W = H;

    const int b = (box >= N_PER_B) ? 1 : 0;
    feat += (size_t)b * H * W * CCH;

    const float Hm1 = (float)(H - 1);
    const float Wm1 = (float)(W - 1);

    // ys = y1*(H-1) + iy * ((y2-y1)*(H-1)/6)   (match reference exactly)
    const float ys = y1 * Hm1 + (float)iy * (h * Hm1 / 6.0f);
    const bool  vy = (ys >= 0.0f) && (ys <= Hm1);

    const float y0f  = floorf(ys);
    const float wy   = ys - y0f;
    const float omwy = 1.0f - wy;

    const int y0i = (int)fminf(fmaxf(y0f,        0.0f), Hm1);
    const int y1i = (int)fminf(fmaxf(y0f + 1.0f, 0.0f), Hm1);

    const float* row0 = feat + (size_t)y0i * W * CCH + c;
    const float* row1 = feat + (size_t)y1i * W * CCH + c;

    const float xstep = w * Wm1 / 6.0f;

    // ---- phase 1: issue all 28 loads ----
    nfloat4 v00[PW], v01[PW], v10[PW], v11[PW];
    float   wxv[PW];
    bool    vxv[PW];

#pragma unroll
    for (int ix = 0; ix < PW; ++ix) {
        const float xs = x1 * Wm1 + (float)ix * xstep;
        vxv[ix] = (xs >= 0.0f) && (xs <= Wm1);
        const float x0f = floorf(xs);
        wxv[ix] = xs - x0f;
        const int x0i = (int)fminf(fmaxf(x0f,        0.0f), Wm1);
        const int x1i = (int)fminf(fmaxf(x0f + 1.0f, 0.0f), Wm1);
        v00[ix] = *(const nfloat4*)(row0 + (size_t)x0i * CCH);
        v01[ix] = *(const nfloat4*)(row0 + (size_t)x1i * CCH);
        v10[ix] = *(const nfloat4*)(row1 + (size_t)x0i * CCH);
        v11[ix] = *(const nfloat4*)(row1 + (size_t)x1i * CCH);
    }

    // ---- phase 2: lerp + nontemporal store ----
    float* dst_base = out + ((size_t)box * (PH * PW) + (size_t)iy * PW) * CCH + c;

#pragma unroll
    for (int ix = 0; ix < PW; ++ix) {
        const float wx   = wxv[ix];
        const float omwx = 1.0f - wx;

        nfloat4 res = (v00[ix] * omwx + v01[ix] * wx) * omwy
                    + (v10[ix] * omwx + v11[ix] * wx) * wy;

        if (!(vy && vxv[ix])) res = (nfloat4)0.0f;

        __builtin_nontemporal_store(res, (nfloat4*)(dst_base + (size_t)ix * CCH));
    }
}

extern "C" void kernel_launch(void* const* d_in, const int* in_sizes, int n_in,
                              void* d_out, int out_size, void* d_ws, size_t ws_size,
                              hipStream_t stream) {
    const float* boxes = (const float*)d_in[0];
    // d_in[1] = positive_indices (unused by reference)
    const float* p3 = (const float*)d_in[2];
    const float* p4 = (const float*)d_in[3];
    const float* p5 = (const float*)d_in[4];
    // d_in[5] = config (unused)
    float* out = (float*)d_out;

    const int grid = TOTAL_WAVES / WAVES_PER_BLOCK;   // 3500 blocks, exact
    hipLaunchKernelGGL(pyramid_roi_align_kernel, dim3(grid), dim3(256), 0, stream,
                       boxes, p3, p4, p5, out);
}